// Round 5
// baseline (247.214 us; speedup 1.0000x reference)
//
#include <hip/hip_runtime.h>

// Problem constants (fixed by reference setup_inputs)
#define BN 32768      // batch
#define DN 1024       // feature dim
#define CN 256        // num classes
#define RCAP 320      // max class size tracked (counts ~128 +/- 11; 320 = ~17 sigma)

__device__ __forceinline__ float dot4(float4 a, float4 b) {
    return a.x*b.x + a.y*b.y + a.z*b.z + a.w*b.w;
}

// ---------------------------------------------------------------------------
// PASS A -- K_NORM v2: streaming row norms with DEEP load queue.
// 512 blocks x 512 thr = 4096 waves; wave gw owns rows [gw*8, gw*8+8) as
// 2 batches of 4 rows. Each batch issues 16 independent global_load_dwordx4
// (16 KB in flight per wave) before any use; the 4 norm shuffle-chains are
// independent and pipeline through the DS unit. launch_bounds(512,4):
// VGPR cap 128 (16 f4 live = 64 VGPR + misc fits), 16 waves/CU.
// H3 probe: if in-flight depth is the lever, this runs ~22 us (~6 TB/s).
// ---------------------------------------------------------------------------
__global__ void __launch_bounds__(512, 4) k_norm(const float4* __restrict__ x4,
                                                 float* __restrict__ rnorm) {
    const int lane = threadIdx.x & 63;
    const int gw = (int)((blockIdx.x * 512u + threadIdx.x) >> 6);   // 0..4095
#pragma unroll
    for (int b = 0; b < 2; ++b) {
        const int row0 = gw * 8 + b * 4;
        const float4* p0 = x4 + (size_t)(row0 + 0) * 256;
        const float4* p1 = x4 + (size_t)(row0 + 1) * 256;
        const float4* p2 = x4 + (size_t)(row0 + 2) * 256;
        const float4* p3 = x4 + (size_t)(row0 + 3) * 256;
        const float4 u00 = p0[lane], u01 = p0[lane + 64], u02 = p0[lane + 128], u03 = p0[lane + 192];
        const float4 u10 = p1[lane], u11 = p1[lane + 64], u12 = p1[lane + 128], u13 = p1[lane + 192];
        const float4 u20 = p2[lane], u21 = p2[lane + 64], u22 = p2[lane + 128], u23 = p2[lane + 192];
        const float4 u30 = p3[lane], u31 = p3[lane + 64], u32 = p3[lane + 128], u33 = p3[lane + 192];
        float s0 = dot4(u00, u00) + dot4(u01, u01) + dot4(u02, u02) + dot4(u03, u03);
        float s1 = dot4(u10, u10) + dot4(u11, u11) + dot4(u12, u12) + dot4(u13, u13);
        float s2 = dot4(u20, u20) + dot4(u21, u21) + dot4(u22, u22) + dot4(u23, u23);
        float s3 = dot4(u30, u30) + dot4(u31, u31) + dot4(u32, u32) + dot4(u33, u33);
#pragma unroll
        for (int off = 32; off; off >>= 1) {
            s0 += __shfl_xor(s0, off, 64);
            s1 += __shfl_xor(s1, off, 64);
            s2 += __shfl_xor(s2, off, 64);
            s3 += __shfl_xor(s3, off, 64);
        }
        if (lane == 0) {
            ((float4*)rnorm)[row0 >> 2] = make_float4(
                1.0f / fmaxf(sqrtf(s0), 1e-12f),
                1.0f / fmaxf(sqrtf(s1), 1e-12f),
                1.0f / fmaxf(sqrtf(s2), 1e-12f),
                1.0f / fmaxf(sqrtf(s3), 1e-12f));
        }
    }
}

// ---------------------------------------------------------------------------
// PASS B -- K_ACC v2: one block (1024 thr / 16 waves) per class, gather with
// DEEP load queue: 4 rows per wave-batch = 16 dwordx4 in flight, body is
// loads+fmac only (norms precomputed). launch_bounds(1024,4) raises the
// VGPR cap to 128 (the R4 build sat at 48 VGPR under the default cap, which
// prevents any load-batch depth). Compaction + epilogue verbatim from the
// passing round-4 kernel.
// ---------------------------------------------------------------------------
__global__ void __launch_bounds__(1024, 4) k_acc(const float4* __restrict__ x4,
                                                 const int* __restrict__ labels,
                                                 const float* __restrict__ rnorm,
                                                 float* __restrict__ out) {
    __shared__ unsigned int packed[BN / 4];   // 32 KB: 4 labels per word
    __shared__ int sic[RCAP];                 // ordered member list (global rows)
    __shared__ float rnl[RCAP];               // 1/||x_row|| per member position
    __shared__ int wcnt[16];
    __shared__ float fa[(DN / 4) * 5];        // 5 KB, stride-5 padded quads
    __shared__ float wred[4];
    __shared__ float4 cred[4];

    const int c = blockIdx.x;
    const int t = threadIdx.x;

    // ---- stage labels (8192 words / 1024 thr = 8 int4 loads each) ----
    for (int w = t; w < BN / 4; w += 1024) {
        const int4 v = ((const int4*)labels)[w];
        packed[w] = (unsigned int)(v.x & 255)
                  | ((unsigned int)(v.y & 255) << 8)
                  | ((unsigned int)(v.z & 255) << 16)
                  | ((unsigned int)(v.w & 255) << 24);
    }
    for (int i = t; i < (DN / 4) * 5; i += 1024) fa[i] = 0.0f;
    __syncthreads();

    const int wave = t >> 6, lane = t & 63;
    const unsigned long long lt = (lane == 0) ? 0ull : (~0ull >> (64 - lane));
    const int ch0 = wave * 32, ch1 = ch0 + 32;  // 32 chunks of 64 per wave

    // ---- pass 1: count ----
    int cnt = 0;
    for (int ch = ch0; ch < ch1; ++ch) {
        const int gi = ch * 64 + lane;
        const int lab = (packed[gi >> 2] >> ((gi & 3) * 8)) & 255;
        cnt += __popcll(__ballot(lab == c));
    }
    if (lane == 0) wcnt[wave] = cnt;
    __syncthreads();

    int base = 0, ntot = 0;
    for (int w2 = 0; w2 < 16; ++w2) {
        const int v = wcnt[w2];
        if (w2 < wave) base += v;
        ntot += v;
    }

    // ---- pass 2: ordered member list + staged norms (LDS only) ----
    for (int ch = ch0; ch < ch1; ++ch) {
        const int gi = ch * 64 + lane;
        const int lab = (packed[gi >> 2] >> ((gi & 3) * 8)) & 255;
        const bool pred = (lab == c);
        const unsigned long long mask = __ballot(pred);
        if (pred) {
            const int pos = base + __popcll(mask & lt);
            if (pos < RCAP) {
                sic[pos] = gi;
                rnl[pos] = rnorm[gi];   // scattered 4B load, L2-hot from k_norm
            }
        }
        base += __popcll(mask);
    }
    __syncthreads();

    // ---- gather + scaled accumulate: 4 rows / wave-batch, 16 loads deep ----
    const int nn = min(ntot, RCAP);
    float4 a0 = make_float4(0.f, 0.f, 0.f, 0.f), a1 = a0, a2 = a0, a3 = a0;
    for (int p0 = wave * 4; p0 < nn; p0 += 64) {   // 16 waves x 4 positions
        const int i1 = min(p0 + 1, nn - 1);
        const int i2 = min(p0 + 2, nn - 1);
        const int i3 = min(p0 + 3, nn - 1);
        const int r0 = sic[p0], r1 = sic[i1], r2 = sic[i2], r3 = sic[i3];
        const float n0 = rnl[p0];
        const float n1 = (p0 + 1 < nn) ? rnl[i1] : 0.0f;  // zero-scale dup tail
        const float n2 = (p0 + 2 < nn) ? rnl[i2] : 0.0f;
        const float n3 = (p0 + 3 < nn) ? rnl[i3] : 0.0f;
        const float4* b0 = x4 + (size_t)r0 * 256;
        const float4* b1 = x4 + (size_t)r1 * 256;
        const float4* b2 = x4 + (size_t)r2 * 256;
        const float4* b3 = x4 + (size_t)r3 * 256;
        const float4 u00 = b0[lane], u01 = b0[lane + 64], u02 = b0[lane + 128], u03 = b0[lane + 192];
        const float4 u10 = b1[lane], u11 = b1[lane + 64], u12 = b1[lane + 128], u13 = b1[lane + 192];
        const float4 u20 = b2[lane], u21 = b2[lane + 64], u22 = b2[lane + 128], u23 = b2[lane + 192];
        const float4 u30 = b3[lane], u31 = b3[lane + 64], u32 = b3[lane + 128], u33 = b3[lane + 192];
        a0.x += u00.x * n0 + u10.x * n1 + u20.x * n2 + u30.x * n3;
        a0.y += u00.y * n0 + u10.y * n1 + u20.y * n2 + u30.y * n3;
        a0.z += u00.z * n0 + u10.z * n1 + u20.z * n2 + u30.z * n3;
        a0.w += u00.w * n0 + u10.w * n1 + u20.w * n2 + u30.w * n3;
        a1.x += u01.x * n0 + u11.x * n1 + u21.x * n2 + u31.x * n3;
        a1.y += u01.y * n0 + u11.y * n1 + u21.y * n2 + u31.y * n3;
        a1.z += u01.z * n0 + u11.z * n1 + u21.z * n2 + u31.z * n3;
        a1.w += u01.w * n0 + u11.w * n1 + u21.w * n2 + u31.w * n3;
        a2.x += u02.x * n0 + u12.x * n1 + u22.x * n2 + u32.x * n3;
        a2.y += u02.y * n0 + u12.y * n1 + u22.y * n2 + u32.y * n3;
        a2.z += u02.z * n0 + u12.z * n1 + u22.z * n2 + u32.z * n3;
        a2.w += u02.w * n0 + u12.w * n1 + u22.w * n2 + u32.w * n3;
        a3.x += u03.x * n0 + u13.x * n1 + u23.x * n2 + u33.x * n3;
        a3.y += u03.y * n0 + u13.y * n1 + u23.y * n2 + u33.y * n3;
        a3.z += u03.z * n0 + u13.z * n1 + u23.z * n2 + u33.z * n3;
        a3.w += u03.w * n0 + u13.w * n1 + u23.w * n2 + u33.w * n3;
    }

    // ---- reduce 16 waves into padded LDS (quad q at fa[5q..5q+3]) ----
    {
        const int q0 = lane, q1 = lane + 64, q2 = lane + 128, q3 = lane + 192;
        atomicAdd(&fa[5 * q0 + 0], a0.x); atomicAdd(&fa[5 * q0 + 1], a0.y);
        atomicAdd(&fa[5 * q0 + 2], a0.z); atomicAdd(&fa[5 * q0 + 3], a0.w);
        atomicAdd(&fa[5 * q1 + 0], a1.x); atomicAdd(&fa[5 * q1 + 1], a1.y);
        atomicAdd(&fa[5 * q1 + 2], a1.z); atomicAdd(&fa[5 * q1 + 3], a1.w);
        atomicAdd(&fa[5 * q2 + 0], a2.x); atomicAdd(&fa[5 * q2 + 1], a2.y);
        atomicAdd(&fa[5 * q2 + 2], a2.z); atomicAdd(&fa[5 * q2 + 3], a2.w);
        atomicAdd(&fa[5 * q3 + 0], a3.x); atomicAdd(&fa[5 * q3 + 1], a3.y);
        atomicAdd(&fa[5 * q3 + 2], a3.z); atomicAdd(&fa[5 * q3 + 3], a3.w);
    }
    __syncthreads();

    // ---- S (quad per thread t<256) and ||S||^2 ----
    float4 Sq = make_float4(0.f, 0.f, 0.f, 0.f);
    float d = 0.0f;
    if (t < 256) {
        Sq.x = fa[5 * t + 0]; Sq.y = fa[5 * t + 1];
        Sq.z = fa[5 * t + 2]; Sq.w = fa[5 * t + 3];
        d = dot4(Sq, Sq);
    }
    if (wave < 4) {
#pragma unroll
        for (int off = 32; off; off >>= 1) d += __shfl_xor(d, off, 64);
        if (lane == 0) wred[wave] = d;
    }
    __syncthreads();

    const int n = ntot;
    if (n >= 2) {                       // uniform across block
        const float s2 = wred[0] + wred[1] + wred[2] + wred[3];
        const int nlim = min(n, nn);
        float dacc = 0.0f;              // only t==0's copy is used
        for (int p = 0; p < nn; ++p) {
            const int j = sic[p];
            if (j >= nlim) continue;    // this member has no exclusion (uniform)
            const int k = sic[j];       // member at in-class position j
            if (t < 256) {
                const float4 xi = x4[(size_t)j * 256 + t];
                const float4 xk = x4[(size_t)k * 256 + t];
                float d0 = dot4(xi, Sq);
                float d1 = dot4(xi, xk);
                float d2 = dot4(xk, Sq);
                float d3 = dot4(xk, xk);
#pragma unroll
                for (int off = 32; off; off >>= 1) {
                    d0 += __shfl_xor(d0, off, 64);
                    d1 += __shfl_xor(d1, off, 64);
                    d2 += __shfl_xor(d2, off, 64);
                    d3 += __shfl_xor(d3, off, 64);
                }
                if (lane == 0) cred[wave] = make_float4(d0, d1, d2, d3);
            }
            __syncthreads();
            if (t == 0) {
                const float xiS  = cred[0].x + cred[1].x + cred[2].x + cred[3].x;
                const float xixk = cred[0].y + cred[1].y + cred[2].y + cred[3].y;
                const float xkS  = cred[0].z + cred[1].z + cred[2].z + cred[3].z;
                const float xkxk = cred[0].w + cred[1].w + cred[2].w + cred[3].w;
                const float rni = rnl[p];   // norm of row j (member at position p)
                const float rnk = rnl[j];   // norm of row k (member at position j)
                const float fiS  = rni * xiS;
                const float fifk = rni * rnk * xixk;
                const float Sfk  = rnk * xkS;
                const float fk2  = rnk * rnk * xkxk;
                const float nf = (float)n;
                const float dd = nf - 1.0f;
                const float naive = -2.0f * fiS / nf + s2 / (nf * nf);
                const float corr  = -2.0f * (fiS - fifk) / dd
                                  + (s2 - 2.0f * Sfk + fk2) / (dd * dd);
                dacc += corr - naive;
            }
            __syncthreads();   // protect cred reuse next iteration
        }
        if (t == 0) {
            const float nf = (float)n;
            const float total = (nf - s2 / nf) + dacc;
            atomicAdd(out, total * (1.0f / DN) * (0.0005f / (float)BN));
        }
    }
}

extern "C" void kernel_launch(void* const* d_in, const int* in_sizes, int n_in,
                              void* d_out, int out_size, void* d_ws, size_t ws_size,
                              hipStream_t stream) {
    const float4* x4 = (const float4*)d_in[0];
    const int* labels = (const int*)d_in[1];
    float* out = (float*)d_out;

    // ws layout: rnorm only (128 KB << budget)
    float* rnorm = (float*)d_ws;

    hipMemsetAsync(out, 0, sizeof(float), stream);
    k_norm<<<512, 512, 0, stream>>>(x4, rnorm);
    k_acc<<<CN, 1024, 0, stream>>>(x4, labels, rnorm, out);
}

// Round 6
// 227.527 us; speedup vs baseline: 1.0865x; 1.0865x over previous
//
#include <hip/hip_runtime.h>

// Problem constants (fixed by reference setup_inputs)
#define BN 32768      // batch
#define DN 1024       // feature dim
#define CN 256        // num classes
#define RCAP 320      // max class size tracked (counts ~128 +/- 11; 320 = ~17 sigma)

__device__ __forceinline__ float dot4(float4 a, float4 b) {
    return a.x*b.x + a.y*b.y + a.z*b.z + a.w*b.w;
}

// ---------------------------------------------------------------------------
// K_ALL: one block (1024 thr / 16 waves) per class. Fully fused, read-once.
// Structure = round-0 k_main (best measured gather: 1 row/wave-iter, no
// duplicate tail loads) + round-3 fused epilogue (corrections in-block).
//  1) stage all labels to LDS packed as bytes (32 KB)
//  2) compaction pass 1: ballot-count per chunk, SAVING each chunk's 64-bit
//     ballot mask in LDS (smask, 4 KB) -- pass 2 replays masks instead of
//     re-reading labels + re-balloting (halves compaction work)
//  3) gather: wave w takes member positions r = w, w+16, ...: load full 4 KB
//     row (4 dwordx4), xor-shuffle row norm, write rn to LDS rnl[r],
//     accumulate x*rn into wave-private regs. Features read EXACTLY ONCE.
//     NOTE: scattered 4KB-row reads are DRAM-page-locality bound (~1.8 TB/s
//     device-wide); occupancy/ILP/queue-depth changes were all measured null
//     (rounds 2/4/5). Do not add unrolling: duplicate tail loads cost ~10%.
//  4) block-reduce wave accumulators via stride-5-padded LDS atomics
//     (proven conflict-free; SQ_LDS_BANK_CONFLICT == 0)
//  5) fused exclusion corrections (~0.5/class): member at position p (row
//     j=sic[p]) has an exclusion iff j < n; excluded member k = sic[j].
//     Rows j,k re-read (L1/L2-hot). Norms from LDS rnl.
//  6) single pre-scaled atomicAdd into out. 2 dispatches total.
// ---------------------------------------------------------------------------
__global__ void __launch_bounds__(1024) k_all(const float4* __restrict__ x4,
                                              const int* __restrict__ labels,
                                              float* __restrict__ out) {
    __shared__ unsigned int packed[BN / 4];       // 32 KB: 4 labels per word
    __shared__ unsigned long long smask[BN / 64]; // 4 KB: per-chunk ballot masks
    __shared__ int sic[RCAP];                     // ordered member list (rows)
    __shared__ float rnl[RCAP];                   // 1/||x_row|| per position
    __shared__ int wcnt[16];
    __shared__ float fa[(DN / 4) * 5];            // 5 KB, stride-5 padded quads
    __shared__ float wred[4];
    __shared__ float4 cred[4];

    const int c = blockIdx.x;
    const int t = threadIdx.x;

    // ---- stage labels (8192 words / 1024 thr = 8 int4 loads each) ----
    for (int w = t; w < BN / 4; w += 1024) {
        const int4 v = ((const int4*)labels)[w];
        packed[w] = (unsigned int)(v.x & 255)
                  | ((unsigned int)(v.y & 255) << 8)
                  | ((unsigned int)(v.z & 255) << 16)
                  | ((unsigned int)(v.w & 255) << 24);
    }
    for (int i = t; i < (DN / 4) * 5; i += 1024) fa[i] = 0.0f;
    __syncthreads();

    const int wave = t >> 6, lane = t & 63;
    const unsigned long long lt = (lane == 0) ? 0ull : (~0ull >> (64 - lane));
    const int ch0 = wave * 32, ch1 = ch0 + 32;  // 32 chunks of 64 per wave

    // ---- pass 1: count + save ballot masks ----
    int cnt = 0;
    for (int ch = ch0; ch < ch1; ++ch) {
        const int gi = ch * 64 + lane;
        const int lab = (packed[gi >> 2] >> ((gi & 3) * 8)) & 255;
        const unsigned long long mask = __ballot(lab == c);
        if (lane == 0) smask[ch] = mask;
        cnt += __popcll(mask);
    }
    if (lane == 0) wcnt[wave] = cnt;
    __syncthreads();

    int base = 0, ntot = 0;
    for (int w2 = 0; w2 < 16; ++w2) {
        const int v = wcnt[w2];
        if (w2 < wave) base += v;
        ntot += v;
    }

    // ---- pass 2: ordered member list from saved masks (no label re-read) ----
    for (int ch = ch0; ch < ch1; ++ch) {
        const unsigned long long mask = smask[ch];   // LDS broadcast
        if ((mask >> lane) & 1ull) {
            const int pos = base + __popcll(mask & lt);
            if (pos < RCAP) sic[pos] = ch * 64 + lane;
        }
        base += __popcll(mask);
    }
    __syncthreads();

    // ---- gather + row norm + scaled accumulate (1 row / wave-iteration) ----
    const int nn = min(ntot, RCAP);
    float4 a0 = make_float4(0.f, 0.f, 0.f, 0.f), a1 = a0, a2 = a0, a3 = a0;
    for (int r = wave; r < nn; r += 16) {
        const int row = sic[r];
        const float4* b4 = x4 + (size_t)row * 256;
        const float4 v0 = b4[lane];
        const float4 v1 = b4[lane + 64];
        const float4 v2 = b4[lane + 128];
        const float4 v3 = b4[lane + 192];
        float ss = dot4(v0, v0) + dot4(v1, v1) + dot4(v2, v2) + dot4(v3, v3);
#pragma unroll
        for (int off = 32; off; off >>= 1) ss += __shfl_xor(ss, off, 64);
        const float rn = 1.0f / fmaxf(sqrtf(ss), 1e-12f);
        if (lane == 0) rnl[r] = rn;
        a0.x += v0.x * rn; a0.y += v0.y * rn; a0.z += v0.z * rn; a0.w += v0.w * rn;
        a1.x += v1.x * rn; a1.y += v1.y * rn; a1.z += v1.z * rn; a1.w += v1.w * rn;
        a2.x += v2.x * rn; a2.y += v2.y * rn; a2.z += v2.z * rn; a2.w += v2.w * rn;
        a3.x += v3.x * rn; a3.y += v3.y * rn; a3.z += v3.z * rn; a3.w += v3.w * rn;
    }

    // ---- reduce 16 waves into padded LDS (quad q at fa[5q..5q+3]) ----
    {
        const int q0 = lane, q1 = lane + 64, q2 = lane + 128, q3 = lane + 192;
        atomicAdd(&fa[5 * q0 + 0], a0.x); atomicAdd(&fa[5 * q0 + 1], a0.y);
        atomicAdd(&fa[5 * q0 + 2], a0.z); atomicAdd(&fa[5 * q0 + 3], a0.w);
        atomicAdd(&fa[5 * q1 + 0], a1.x); atomicAdd(&fa[5 * q1 + 1], a1.y);
        atomicAdd(&fa[5 * q1 + 2], a1.z); atomicAdd(&fa[5 * q1 + 3], a1.w);
        atomicAdd(&fa[5 * q2 + 0], a2.x); atomicAdd(&fa[5 * q2 + 1], a2.y);
        atomicAdd(&fa[5 * q2 + 2], a2.z); atomicAdd(&fa[5 * q2 + 3], a2.w);
        atomicAdd(&fa[5 * q3 + 0], a3.x); atomicAdd(&fa[5 * q3 + 1], a3.y);
        atomicAdd(&fa[5 * q3 + 2], a3.z); atomicAdd(&fa[5 * q3 + 3], a3.w);
    }
    __syncthreads();

    // ---- S (quad per thread t<256) and ||S||^2 ----
    float4 Sq = make_float4(0.f, 0.f, 0.f, 0.f);
    float d = 0.0f;
    if (t < 256) {
        Sq.x = fa[5 * t + 0]; Sq.y = fa[5 * t + 1];
        Sq.z = fa[5 * t + 2]; Sq.w = fa[5 * t + 3];
        d = dot4(Sq, Sq);
    }
    if (wave < 4) {
#pragma unroll
        for (int off = 32; off; off >>= 1) d += __shfl_xor(d, off, 64);
        if (lane == 0) wred[wave] = d;
    }
    __syncthreads();

    const int n = ntot;
    if (n >= 2) {                       // uniform across block
        const float s2 = wred[0] + wred[1] + wred[2] + wred[3];
        const int nlim = min(n, nn);
        float dacc = 0.0f;              // only t==0's copy is used
        for (int p = 0; p < nn; ++p) {
            const int j = sic[p];
            if (j >= nlim) continue;    // this member has no exclusion (uniform)
            const int k = sic[j];       // member at in-class position j
            if (t < 256) {
                const float4 xi = x4[(size_t)j * 256 + t];
                const float4 xk = x4[(size_t)k * 256 + t];
                float d0 = dot4(xi, Sq);
                float d1 = dot4(xi, xk);
                float d2 = dot4(xk, Sq);
                float d3 = dot4(xk, xk);
#pragma unroll
                for (int off = 32; off; off >>= 1) {
                    d0 += __shfl_xor(d0, off, 64);
                    d1 += __shfl_xor(d1, off, 64);
                    d2 += __shfl_xor(d2, off, 64);
                    d3 += __shfl_xor(d3, off, 64);
                }
                if (lane == 0) cred[wave] = make_float4(d0, d1, d2, d3);
            }
            __syncthreads();
            if (t == 0) {
                const float xiS  = cred[0].x + cred[1].x + cred[2].x + cred[3].x;
                const float xixk = cred[0].y + cred[1].y + cred[2].y + cred[3].y;
                const float xkS  = cred[0].z + cred[1].z + cred[2].z + cred[3].z;
                const float xkxk = cred[0].w + cred[1].w + cred[2].w + cred[3].w;
                const float rni = rnl[p];   // norm of row j (member at position p)
                const float rnk = rnl[j];   // norm of row k (member at position j)
                const float fiS  = rni * xiS;
                const float fifk = rni * rnk * xixk;
                const float Sfk  = rnk * xkS;
                const float fk2  = rnk * rnk * xkxk;
                const float nf = (float)n;
                const float dd = nf - 1.0f;
                const float naive = -2.0f * fiS / nf + s2 / (nf * nf);
                const float corr  = -2.0f * (fiS - fifk) / dd
                                  + (s2 - 2.0f * Sfk + fk2) / (dd * dd);
                dacc += corr - naive;
            }
            __syncthreads();   // protect cred reuse next iteration
        }
        if (t == 0) {
            const float nf = (float)n;
            const float total = (nf - s2 / nf) + dacc;
            atomicAdd(out, total * (1.0f / DN) * (0.0005f / (float)BN));
        }
    }
}

extern "C" void kernel_launch(void* const* d_in, const int* in_sizes, int n_in,
                              void* d_out, int out_size, void* d_ws, size_t ws_size,
                              hipStream_t stream) {
    const float4* x4 = (const float4*)d_in[0];
    const int* labels = (const int*)d_in[1];
    float* out = (float*)d_out;

    hipMemsetAsync(out, 0, sizeof(float), stream);
    k_all<<<CN, 1024, 0, stream>>>(x4, labels, out);
}

// Round 7
// 219.840 us; speedup vs baseline: 1.1245x; 1.0350x over previous
//
#include <hip/hip_runtime.h>

// Problem constants (fixed by reference setup_inputs)
#define BN 32768      // batch
#define DN 1024       // feature dim
#define CN 256        // num classes
#define RCAP 320      // max class size tracked (counts ~128 +/- 11; 320 = ~17 sigma)

__device__ __forceinline__ float dot4(float4 a, float4 b) {
    return a.x*b.x + a.y*b.y + a.z*b.z + a.w*b.w;
}

// ---------------------------------------------------------------------------
// K_ALL: one block (1024 thr / 16 waves) per class. Fully fused, read-once.
// Measurement ledger (all on this problem, MI355X):
//   - gather is pinned at ~1.7-1.8 TB/s device-wide regardless of occupancy
//     (R2: 32 waves/CU null), chain removal (R4 null), load depth (R5 null),
//     unrolling (R3/R5 ~neutral). 1-row/wave-iter is the proven best shape.
//   - fused SERIAL corrections cost +12 us via worst-block tail (R6 vs R0);
//     this version runs corrections wave-parallel (no intra-loop barriers).
// Phases:
//  1) stage labels packed as bytes (32 KB LDS)
//  2) compaction: ballot-count saving per-chunk masks (smask); replay masks
//     for the ordered member list sic[] (no label re-read)
//  3) gather: wave w takes positions r = w, w+16, ...: load full 4 KB row,
//     xor-shuffle row norm, rnl[r] = rn, accumulate x*rn in wave regs
//  4) block-reduce wave accumulators via stride-5-padded LDS atomics
//     (proven conflict-free; SQ_LDS_BANK_CONFLICT == 0)
//  5) corrections WAVE-PARALLEL: wave w handles p = w, w+16, ... with
//     exclusion iff j=sic[p] < n; k=sic[j]; S read from padded fa (stride-5
//     -> 2-way bank aliasing only, free); delta atomicAdd'd to LDS scalar
//  6) single pre-scaled atomicAdd into out. 2 dispatches total.
// ---------------------------------------------------------------------------
__global__ void __launch_bounds__(1024) k_all(const float4* __restrict__ x4,
                                              const int* __restrict__ labels,
                                              float* __restrict__ out) {
    __shared__ unsigned int packed[BN / 4];       // 32 KB: 4 labels per word
    __shared__ unsigned long long smask[BN / 64]; // 4 KB: per-chunk ballot masks
    __shared__ int sic[RCAP];                     // ordered member list (rows)
    __shared__ float rnl[RCAP];                   // 1/||x_row|| per position
    __shared__ int wcnt[16];
    __shared__ float fa[(DN / 4) * 5];            // 5 KB, stride-5 padded quads
    __shared__ float wred[4];
    __shared__ float dacc_s;                      // correction delta accumulator

    const int c = blockIdx.x;
    const int t = threadIdx.x;

    // ---- stage labels (8192 words / 1024 thr = 8 int4 loads each) ----
    for (int w = t; w < BN / 4; w += 1024) {
        const int4 v = ((const int4*)labels)[w];
        packed[w] = (unsigned int)(v.x & 255)
                  | ((unsigned int)(v.y & 255) << 8)
                  | ((unsigned int)(v.z & 255) << 16)
                  | ((unsigned int)(v.w & 255) << 24);
    }
    for (int i = t; i < (DN / 4) * 5; i += 1024) fa[i] = 0.0f;
    if (t == 0) dacc_s = 0.0f;
    __syncthreads();

    const int wave = t >> 6, lane = t & 63;
    const unsigned long long lt = (lane == 0) ? 0ull : (~0ull >> (64 - lane));
    const int ch0 = wave * 32, ch1 = ch0 + 32;  // 32 chunks of 64 per wave

    // ---- pass 1: count + save ballot masks ----
    int cnt = 0;
    for (int ch = ch0; ch < ch1; ++ch) {
        const int gi = ch * 64 + lane;
        const int lab = (packed[gi >> 2] >> ((gi & 3) * 8)) & 255;
        const unsigned long long mask = __ballot(lab == c);
        if (lane == 0) smask[ch] = mask;
        cnt += __popcll(mask);
    }
    if (lane == 0) wcnt[wave] = cnt;
    __syncthreads();

    int base = 0, ntot = 0;
    for (int w2 = 0; w2 < 16; ++w2) {
        const int v = wcnt[w2];
        if (w2 < wave) base += v;
        ntot += v;
    }

    // ---- pass 2: ordered member list from saved masks ----
    for (int ch = ch0; ch < ch1; ++ch) {
        const unsigned long long mask = smask[ch];   // LDS broadcast
        if ((mask >> lane) & 1ull) {
            const int pos = base + __popcll(mask & lt);
            if (pos < RCAP) sic[pos] = ch * 64 + lane;
        }
        base += __popcll(mask);
    }
    __syncthreads();

    // ---- gather + row norm + scaled accumulate (1 row / wave-iteration) ----
    const int nn = min(ntot, RCAP);
    float4 a0 = make_float4(0.f, 0.f, 0.f, 0.f), a1 = a0, a2 = a0, a3 = a0;
    for (int r = wave; r < nn; r += 16) {
        const int row = sic[r];
        const float4* b4 = x4 + (size_t)row * 256;
        const float4 v0 = b4[lane];
        const float4 v1 = b4[lane + 64];
        const float4 v2 = b4[lane + 128];
        const float4 v3 = b4[lane + 192];
        float ss = dot4(v0, v0) + dot4(v1, v1) + dot4(v2, v2) + dot4(v3, v3);
#pragma unroll
        for (int off = 32; off; off >>= 1) ss += __shfl_xor(ss, off, 64);
        const float rn = 1.0f / fmaxf(sqrtf(ss), 1e-12f);
        if (lane == 0) rnl[r] = rn;
        a0.x += v0.x * rn; a0.y += v0.y * rn; a0.z += v0.z * rn; a0.w += v0.w * rn;
        a1.x += v1.x * rn; a1.y += v1.y * rn; a1.z += v1.z * rn; a1.w += v1.w * rn;
        a2.x += v2.x * rn; a2.y += v2.y * rn; a2.z += v2.z * rn; a2.w += v2.w * rn;
        a3.x += v3.x * rn; a3.y += v3.y * rn; a3.z += v3.z * rn; a3.w += v3.w * rn;
    }

    // ---- reduce 16 waves into padded LDS (quad q at fa[5q..5q+3]) ----
    {
        const int q0 = lane, q1 = lane + 64, q2 = lane + 128, q3 = lane + 192;
        atomicAdd(&fa[5 * q0 + 0], a0.x); atomicAdd(&fa[5 * q0 + 1], a0.y);
        atomicAdd(&fa[5 * q0 + 2], a0.z); atomicAdd(&fa[5 * q0 + 3], a0.w);
        atomicAdd(&fa[5 * q1 + 0], a1.x); atomicAdd(&fa[5 * q1 + 1], a1.y);
        atomicAdd(&fa[5 * q1 + 2], a1.z); atomicAdd(&fa[5 * q1 + 3], a1.w);
        atomicAdd(&fa[5 * q2 + 0], a2.x); atomicAdd(&fa[5 * q2 + 1], a2.y);
        atomicAdd(&fa[5 * q2 + 2], a2.z); atomicAdd(&fa[5 * q2 + 3], a2.w);
        atomicAdd(&fa[5 * q3 + 0], a3.x); atomicAdd(&fa[5 * q3 + 1], a3.y);
        atomicAdd(&fa[5 * q3 + 2], a3.z); atomicAdd(&fa[5 * q3 + 3], a3.w);
    }
    __syncthreads();

    // ---- ||S||^2 (threads t<256 hold one quad each, 4-wave reduce) ----
    float d = 0.0f;
    if (t < 256) {
        float4 Sq;
        Sq.x = fa[5 * t + 0]; Sq.y = fa[5 * t + 1];
        Sq.z = fa[5 * t + 2]; Sq.w = fa[5 * t + 3];
        d = dot4(Sq, Sq);
    }
    if (wave < 4) {
#pragma unroll
        for (int off = 32; off; off >>= 1) d += __shfl_xor(d, off, 64);
        if (lane == 0) wred[wave] = d;
    }
    __syncthreads();

    const int n = ntot;
    if (n >= 2) {                       // uniform across block
        const float s2 = wred[0] + wred[1] + wred[2] + wred[3];
        const int nlim = min(n, nn);

        // ---- WAVE-PARALLEL exclusion corrections (no intra-loop barriers).
        // Wave w handles positions p = w, w+16, ...; each correction is one
        // wave's work: 8 loads (rows j,k; L1/L2/L3-hot), S from padded fa
        // (addr 5*q -> gcd(5,32)=1 walks all banks; 2 lanes/bank = free),
        // 4 shuffle-reduce chains, lane0 LDS-atomicAdds the delta.
        for (int p = wave; p < nn; p += 16) {
            const int j = sic[p];
            if (j >= nlim) continue;    // no exclusion for this member (wave-uniform)
            const int k = sic[j];       // member at in-class position j
            const float4* bi = x4 + (size_t)j * 256;
            const float4* bk = x4 + (size_t)k * 256;
            const float4 xi0 = bi[lane], xi1 = bi[lane + 64],
                         xi2 = bi[lane + 128], xi3 = bi[lane + 192];
            const float4 xk0 = bk[lane], xk1 = bk[lane + 64],
                         xk2 = bk[lane + 128], xk3 = bk[lane + 192];
            float4 S0, S1, S2, S3;
            {
                const int q0 = lane, q1 = lane + 64, q2 = lane + 128, q3 = lane + 192;
                S0.x = fa[5*q0+0]; S0.y = fa[5*q0+1]; S0.z = fa[5*q0+2]; S0.w = fa[5*q0+3];
                S1.x = fa[5*q1+0]; S1.y = fa[5*q1+1]; S1.z = fa[5*q1+2]; S1.w = fa[5*q1+3];
                S2.x = fa[5*q2+0]; S2.y = fa[5*q2+1]; S2.z = fa[5*q2+2]; S2.w = fa[5*q2+3];
                S3.x = fa[5*q3+0]; S3.y = fa[5*q3+1]; S3.z = fa[5*q3+2]; S3.w = fa[5*q3+3];
            }
            float d0 = dot4(xi0, S0) + dot4(xi1, S1) + dot4(xi2, S2) + dot4(xi3, S3);
            float d1 = dot4(xi0, xk0) + dot4(xi1, xk1) + dot4(xi2, xk2) + dot4(xi3, xk3);
            float d2 = dot4(xk0, S0) + dot4(xk1, S1) + dot4(xk2, S2) + dot4(xk3, S3);
            float d3 = dot4(xk0, xk0) + dot4(xk1, xk1) + dot4(xk2, xk2) + dot4(xk3, xk3);
#pragma unroll
            for (int off = 32; off; off >>= 1) {
                d0 += __shfl_xor(d0, off, 64);
                d1 += __shfl_xor(d1, off, 64);
                d2 += __shfl_xor(d2, off, 64);
                d3 += __shfl_xor(d3, off, 64);
            }
            if (lane == 0) {
                const float rni = rnl[p];   // norm of row j (position p)
                const float rnk = rnl[j];   // norm of row k (position j)
                const float fiS  = rni * d0;
                const float fifk = rni * rnk * d1;
                const float Sfk  = rnk * d2;
                const float fk2  = rnk * rnk * d3;
                const float nf = (float)n;
                const float dd = nf - 1.0f;
                const float naive = -2.0f * fiS / nf + s2 / (nf * nf);
                const float corr  = -2.0f * (fiS - fifk) / dd
                                  + (s2 - 2.0f * Sfk + fk2) / (dd * dd);
                atomicAdd(&dacc_s, corr - naive);
            }
        }
        __syncthreads();   // all waves' deltas landed in dacc_s
        if (t == 0) {
            const float nf = (float)n;
            const float total = (nf - s2 / nf) + dacc_s;
            atomicAdd(out, total * (1.0f / DN) * (0.0005f / (float)BN));
        }
    }
}

extern "C" void kernel_launch(void* const* d_in, const int* in_sizes, int n_in,
                              void* d_out, int out_size, void* d_ws, size_t ws_size,
                              hipStream_t stream) {
    const float4* x4 = (const float4*)d_in[0];
    const int* labels = (const int*)d_in[1];
    float* out = (float*)d_out;

    hipMemsetAsync(out, 0, sizeof(float), stream);
    k_all<<<CN, 1024, 0, stream>>>(x4, labels, out);
}